// Round 5
// baseline (1083.711 us; speedup 1.0000x reference)
//
#include <hip/hip_runtime.h>
#include <hip/hip_bf16.h>

typedef unsigned short u16;
typedef unsigned int u32;
typedef unsigned long long u64;
typedef __attribute__((ext_vector_type(8))) short short8;
typedef __attribute__((ext_vector_type(4))) float f32x4;

#define TOKENS 4096
#define HDIM 2048
#define NEXP 16
#define IDIM 1024
#define ISH 2048
#define MAXTILES 48  // 256-row tiles: sum ceil(cnt_e/256) <= 32 + 16
#define NCHUNK 128   // 8192 route entries / 64 lanes

#define AS1(p) ((const __attribute__((address_space(1))) u32*)(p))
#define AS3(p) ((__attribute__((address_space(3))) u32*)(p))

__device__ __forceinline__ u16 f2b(float f) {
    u32 u = __float_as_uint(f);
    u32 r = u + 0x7fffu + ((u >> 16) & 1u);
    return (u16)(r >> 16);
}

// ---------------- convert x to bf16 ----------------
__global__ __launch_bounds__(256) void convert_x_kernel(const float* __restrict__ x,
                                                        u16* __restrict__ xb) {
    size_t i = ((size_t)blockIdx.x * 256 + threadIdx.x) * 8;
    float4 a = *(const float4*)(x + i);
    float4 b = *(const float4*)(x + i + 4);
    u32 p0 = (u32)f2b(a.x) | ((u32)f2b(a.y) << 16);
    u32 p1 = (u32)f2b(a.z) | ((u32)f2b(a.w) << 16);
    u32 p2 = (u32)f2b(b.x) | ((u32)f2b(b.y) << 16);
    u32 p3 = (u32)f2b(b.z) | ((u32)f2b(b.w) << 16);
    uint4 o = make_uint4(p0, p1, p2, p3);
    *(uint4*)(xb + i) = o;
}

// ---------------- routing: 1 wave per token, cent staged in LDS ----------------
__global__ __launch_bounds__(256) void route_kernel(const float* __restrict__ x,
                                                    const float* __restrict__ cent,
                                                    const float* __restrict__ bias,
                                                    int* __restrict__ top_e,
                                                    float* __restrict__ top_w) {
    __shared__ alignas(16) float cs[8 * 2048];  // 64KB: 8 experts per phase
    int lane = threadIdx.x & 63;
    int wv = threadIdx.x >> 6;
    int t = blockIdx.x * 4 + wv;
    const float4* xp4 = (const float4*)(x + (size_t)t * HDIM);
    float4 xr[8];
#pragma unroll
    for (int i = 0; i < 8; i++) xr[i] = xp4[lane + 64 * i];
    float aff[16];
#pragma unroll
    for (int ph = 0; ph < 2; ph++) {
        if (ph) __syncthreads();
        const float* sbase = cent + (size_t)(ph * 8 + wv * 2) * HDIM;
        float* dbase = cs + (size_t)wv * 2 * HDIM;
#pragma unroll
        for (int i = 0; i < 16; i++) {
            __builtin_amdgcn_global_load_lds(AS1(sbase + i * 256 + lane * 4),
                                             AS3(dbase + i * 256), 16, 0, 0);
        }
        __syncthreads();
#pragma unroll
        for (int e = 0; e < 8; e++) {
            const float4* cp = (const float4*)cs + (size_t)e * 512;
            float s = 0.f;
#pragma unroll
            for (int i = 0; i < 8; i++) {
                float4 cv = cp[lane + 64 * i];
                s += xr[i].x * cv.x;
                s += xr[i].y * cv.y;
                s += xr[i].z * cv.z;
                s += xr[i].w * cv.w;
            }
#pragma unroll
            for (int off = 32; off > 0; off >>= 1) s += __shfl_xor(s, off, 64);
            aff[ph * 8 + e] = 1.f / (1.f + expf(-s));
        }
    }
    float b0 = -1e30f, b1 = -1e30f, a0 = 0.f, a1 = 0.f;
    int e0 = -1, e1 = -1;
#pragma unroll
    for (int e = 0; e < 16; e++) {
        float v = aff[e] + bias[e];
        if (v > b0) {
            b1 = b0; e1 = e0; a1 = a0;
            b0 = v; e0 = e; a0 = aff[e];
        } else if (v > b1) {
            b1 = v; e1 = e; a1 = aff[e];
        }
    }
    float inv = 1.f / (a0 + a1 + 1e-9f);
    if (lane == 0) {
        top_e[2 * t] = e0; top_w[2 * t] = a0 * inv;
        top_e[2 * t + 1] = e1; top_w[2 * t + 1] = a1 * inv;
    }
}

// ---------------- build: histogram + scan + tile list + scatter, single block ----
// Also emits tok2slot (inverse permutation) for the combine kernel.
__global__ __launch_bounds__(1024) void build_kernel(
    const int* __restrict__ top_e, const float* __restrict__ top_w,
    int* __restrict__ counts, int* __restrict__ offsets, int* __restrict__ ntiles,
    int* __restrict__ tile_e, int* __restrict__ tile_m,
    int* __restrict__ list_tok, float* __restrict__ list_w,
    int* __restrict__ tok2slot) {
    __shared__ int cnt[NCHUNK][16];
    __shared__ int offs_s[16];
    __shared__ int totals[16];
    int tid = threadIdx.x;
    int lane = tid & 63, wv = tid >> 6;  // 16 waves
    for (int c = wv; c < NCHUNK; c += 16) {
        int v = top_e[c * 64 + lane];
#pragma unroll
        for (int e = 0; e < 16; e++) {
            u64 m = __ballot(v == e);
            if (lane == 0) cnt[c][e] = (int)__popcll(m);
        }
    }
    __syncthreads();
    if (tid < 16) {
        int s = 0;
        for (int c = 0; c < NCHUNK; c++) s += cnt[c][tid];
        totals[tid] = s;
        counts[tid] = s;
    }
    __syncthreads();
    if (tid == 0) {
        int r = 0, nt = 0;
        for (int e = 0; e < 16; e++) {
            offs_s[e] = r;
            offsets[e] = r;
            int ce = totals[e];
            int tcnt = (ce + 255) >> 8;  // 256-row tiles
            for (int m = 0; m < tcnt; m++) {
                tile_e[nt] = e;
                tile_m[nt] = m;
                nt++;
            }
            r += ce;
        }
        *ntiles = nt;
    }
    __syncthreads();
    if (tid < 16) {
        int r = offs_s[tid];
        for (int c = 0; c < NCHUNK; c++) {
            int v = cnt[c][tid];
            cnt[c][tid] = r;
            r += v;
        }
    }
    __syncthreads();
    for (int c = wv; c < NCHUNK; c += 16) {
        int i = c * 64 + lane;
        int v = top_e[i];
        int rank = 0;
#pragma unroll
        for (int e = 0; e < 16; e++) {
            u64 m = __ballot(v == e);
            if (v == e) rank = (int)__popcll(m & ((1ull << lane) - 1ull));
        }
        int slot = cnt[c][v] + rank;
        list_tok[slot] = i >> 1;
        list_w[slot] = top_w[i];
        tok2slot[i] = slot;
    }
}

// ================= MAIN PATH =================
// Convert fp32 W[K][N] -> bf16 tiled [N/64][K/32][64][32] with XOR swizzle.
__global__ __launch_bounds__(256) void conv_w_kernel(const float* __restrict__ W,
                                                     u16* __restrict__ Wt, int K, int N) {
    int nt = blockIdx.x, kc = blockIdx.y;
    size_t mato = (size_t)blockIdx.z * K * N;
    const float* Wm = W + mato;
    u16* Wtm = Wt + mato;
    int ksB = K >> 5;
    __shared__ u16 Ls[64 * 40];
    int t = threadIdx.x;
    int kr = t >> 3, ng = t & 7;
    int nn = t >> 2, seg = t & 3;
    int g = seg ^ ((nn >> 2) & 3);
#pragma unroll
    for (int s = 0; s < 8; s++) {
        int kb = kc * 256 + s * 32;
        const float* src = Wm + (size_t)(kb + kr) * N + nt * 64 + ng * 8;
        float4 f0 = *(const float4*)src;
        float4 f1 = *(const float4*)(src + 4);
        __syncthreads();
        const float* p0 = (const float*)&f0;
        const float* p1 = (const float*)&f1;
#pragma unroll
        for (int l = 0; l < 4; l++) Ls[(8 * ng + l) * 40 + kr] = f2b(p0[l]);
#pragma unroll
        for (int l = 0; l < 4; l++) Ls[(8 * ng + 4 + l) * 40 + kr] = f2b(p1[l]);
        __syncthreads();
        const u16* lp = &Ls[nn * 40 + g * 8];
        u32 w0 = (u32)lp[0] | ((u32)lp[1] << 16);
        u32 w1 = (u32)lp[2] | ((u32)lp[3] << 16);
        u32 w2 = (u32)lp[4] | ((u32)lp[5] << 16);
        u32 w3 = (u32)lp[6] | ((u32)lp[7] << 16);
        uint4 o = make_uint4(w0, w1, w2, w3);
        *(uint4*)(Wtm + (size_t)(nt * ksB + (kb >> 5)) * 2048 + t * 8) = o;
    }
}

// fused gate+up: M-tile 256, N-tile 64 (per matrix), BK 32.
// T3-minimum schedule: STAGE(k+1) issued before compute(k), one barrier/step.
// 32 MFMA per wave per synchronized step (2x round-3) to amortize the
// fixed ~1500cy step cost (evidence: down@8 MFMA/step == gateup@16 in time).
__global__ __launch_bounds__(256) void gemm_gateup(
    const u16* __restrict__ A, const u16* __restrict__ BgAll, const u16* __restrict__ BuAll,
    u16* __restrict__ hout, int Kd, int Nout, const int* __restrict__ counts,
    const int* __restrict__ offsets, const int* __restrict__ ntiles,
    const int* __restrict__ tile_e, const int* __restrict__ tile_m,
    const int* __restrict__ list_tok, int routed) {
    int cnt = TOKENS, base = 0, m0;
    const u16* Bg = BgAll;
    const u16* Bu = BuAll;
    if (routed) {
        int ti = blockIdx.x;
        if (ti >= *ntiles) return;
        int e = tile_e[ti];
        m0 = tile_m[ti] * 256;
        cnt = counts[e];
        base = offsets[e];
        size_t off = (size_t)e * Kd * Nout;
        Bg += off; Bu += off;
    } else {
        m0 = blockIdx.x * 256;
    }
    int nk = Kd >> 5;
    __shared__ alignas(16) u16 As[2][256 * 32];   // 16 KB each
    __shared__ alignas(16) u16 Bgs[2][64 * 32];   // 4 KB each
    __shared__ alignas(16) u16 Bus[2][64 * 32];
    int tid = threadIdx.x;
    int lane = tid & 63, wv = tid >> 6;
    int quad = lane >> 4, mr = lane & 15;
    int n0 = blockIdx.y * 64;
    int gk = (tid & 3) ^ ((tid >> 4) & 3);
    const u16* ap0;
    const u16* ap1;
    const u16* ap2;
    const u16* ap3;
    {
        int mg0 = min(m0 + 0 * 64 + (tid >> 2), cnt - 1);
        int mg1 = min(m0 + 1 * 64 + (tid >> 2), cnt - 1);
        int mg2 = min(m0 + 2 * 64 + (tid >> 2), cnt - 1);
        int mg3 = min(m0 + 3 * 64 + (tid >> 2), cnt - 1);
        size_t s0 = routed ? (size_t)list_tok[base + mg0] : (size_t)mg0;
        size_t s1 = routed ? (size_t)list_tok[base + mg1] : (size_t)mg1;
        size_t s2 = routed ? (size_t)list_tok[base + mg2] : (size_t)mg2;
        size_t s3 = routed ? (size_t)list_tok[base + mg3] : (size_t)mg3;
        ap0 = A + s0 * Kd + gk * 8;
        ap1 = A + s1 * Kd + gk * 8;
        ap2 = A + s2 * Kd + gk * 8;
        ap3 = A + s3 * Kd + gk * 8;
    }
    const u16* bgp = Bg + (size_t)blockIdx.y * nk * 2048 + tid * 8;
    const u16* bup = Bu + (size_t)blockIdx.y * nk * 2048 + tid * 8;
    int xq = quad ^ ((mr >> 2) & 3);
    f32x4 accg[4][4], accu[4][4];
#pragma unroll
    for (int i = 0; i < 4; i++)
#pragma unroll
        for (int j = 0; j < 4; j++) { accg[i][j] = (f32x4)0.f; accu[i][j] = (f32x4)0.f; }

#define STAGE_GU(b)                                                                       \
    do {                                                                                  \
        __builtin_amdgcn_global_load_lds(AS1(ap0), AS3(&As[b][0 + wv * 512]), 16, 0, 0);  \
        __builtin_amdgcn_global_load_lds(AS1(ap1), AS3(&As[b][2048 + wv * 512]), 16, 0,   \
                                         0);                                              \
        __builtin_amdgcn_global_load_lds(AS1(ap2), AS3(&As[b][4096 + wv * 512]), 16, 0,   \
                                         0);                                              \
        __builtin_amdgcn_global_load_lds(AS1(ap3), AS3(&As[b][6144 + wv * 512]), 16, 0,   \
                                         0);                                              \
        __builtin_amdgcn_global_load_lds(AS1(bgp), AS3(&Bgs[b][wv * 512]), 16, 0, 0);     \
        __builtin_amdgcn_global_load_lds(AS1(bup), AS3(&Bus[b][wv * 512]), 16, 0, 0);     \
        ap0 += 32; ap1 += 32; ap2 += 32; ap3 += 32; bgp += 2048; bup += 2048;             \
    } while (0)

    STAGE_GU(0);
    __syncthreads();
    int cur = 0;
    for (int ks = 0; ks < nk; ks++) {
        if (ks + 1 < nk) STAGE_GU(cur ^ 1);
        const u16* Asc = As[cur];
        const u16* Bgc = Bgs[cur];
        const u16* Buc = Bus[cur];
        short8 a0 = *(const short8*)(Asc + ((64 * wv + 0 + mr) * 4 + xq) * 8);
        short8 a1 = *(const short8*)(Asc + ((64 * wv + 16 + mr) * 4 + xq) * 8);
        short8 a2 = *(const short8*)(Asc + ((64 * wv + 32 + mr) * 4 + xq) * 8);
        short8 a3 = *(const short8*)(Asc + ((64 * wv + 48 + mr) * 4 + xq) * 8);
#pragma unroll
        for (int j = 0; j < 4; j++) {
            short8 bg = *(const short8*)(Bgc + ((16 * j + mr) * 4 + xq) * 8);
            short8 bu = *(const short8*)(Buc + ((16 * j + mr) * 4 + xq) * 8);
            accg[0][j] = __builtin_amdgcn_mfma_f32_16x16x32_bf16(a0, bg, accg[0][j], 0, 0, 0);
            accg[1][j] = __builtin_amdgcn_mfma_f32_16x16x32_bf16(a1, bg, accg[1][j], 0, 0, 0);
            accg[2][j] = __builtin_amdgcn_mfma_f32_16x16x32_bf16(a2, bg, accg[2][j], 0, 0, 0);
            accg[3][j] = __builtin_amdgcn_mfma_f32_16x16x32_bf16(a3, bg, accg[3][j], 0, 0, 0);
            accu[0][j] = __builtin_amdgcn_mfma_f32_16x16x32_bf16(a0, bu, accu[0][j], 0, 0, 0);
            accu[1][j] = __builtin_amdgcn_mfma_f32_16x16x32_bf16(a1, bu, accu[1][j], 0, 0, 0);
            accu[2][j] = __builtin_amdgcn_mfma_f32_16x16x32_bf16(a2, bu, accu[2][j], 0, 0, 0);
            accu[3][j] = __builtin_amdgcn_mfma_f32_16x16x32_bf16(a3, bu, accu[3][j], 0, 0, 0);
        }
        __syncthreads();
        cur ^= 1;
    }
#undef STAGE_GU

#pragma unroll
    for (int i = 0; i < 4; i++)
#pragma unroll
        for (int j = 0; j < 4; j++)
#pragma unroll
            for (int r = 0; r < 4; r++) {
                int m = m0 + 64 * wv + 16 * i + quad * 4 + r;
                if (m < cnt) {
                    float gv = accg[i][j][r], uv = accu[i][j][r];
                    float h = gv / (1.f + expf(-gv)) * uv;
                    int n = n0 + 16 * j + mr;
                    hout[(size_t)(base + m) * Nout + n] = f2b(h);
                }
            }
}

// down GEMM: M-tile 256, N-tile 64. routed: plain store into per-slot rd buffer
// (atomics removed; combine_kernel gathers). non-routed: out = 0.1*v.
__global__ __launch_bounds__(256) void gemm_down(
    const u16* __restrict__ A, const u16* __restrict__ BAll, float* __restrict__ outp,
    int Kd, const int* __restrict__ counts, const int* __restrict__ offsets,
    const int* __restrict__ ntiles, const int* __restrict__ tile_e,
    const int* __restrict__ tile_m, const int* __restrict__ list_tok, int routed) {
    int cnt = TOKENS, base = 0, m0;
    const u16* B = BAll;
    if (routed) {
        int ti = blockIdx.x;
        if (ti >= *ntiles) return;
        int e = tile_e[ti];
        m0 = tile_m[ti] * 256;
        cnt = counts[e];
        base = offsets[e];
        B += (size_t)e * Kd * HDIM;
    } else {
        m0 = blockIdx.x * 256;
    }
    int nk = Kd >> 5;
    __shared__ alignas(16) u16 As[2][256 * 32];  // 16 KB each
    __shared__ alignas(16) u16 Bs[2][64 * 32];   // 4 KB each
    int tid = threadIdx.x;
    int lane = tid & 63, wv = tid >> 6;
    int quad = lane >> 4, mr = lane & 15;
    int n0 = blockIdx.y * 64;
    int gk = (tid & 3) ^ ((tid >> 4) & 3);
    const u16* ap0;
    const u16* ap1;
    const u16* ap2;
    const u16* ap3;
    {
        int mg0 = base + min(m0 + 0 * 64 + (tid >> 2), cnt - 1);
        int mg1 = base + min(m0 + 1 * 64 + (tid >> 2), cnt - 1);
        int mg2 = base + min(m0 + 2 * 64 + (tid >> 2), cnt - 1);
        int mg3 = base + min(m0 + 3 * 64 + (tid >> 2), cnt - 1);
        ap0 = A + (size_t)mg0 * Kd + gk * 8;
        ap1 = A + (size_t)mg1 * Kd + gk * 8;
        ap2 = A + (size_t)mg2 * Kd + gk * 8;
        ap3 = A + (size_t)mg3 * Kd + gk * 8;
    }
    const u16* bp = B + (size_t)blockIdx.y * nk * 2048 + tid * 8;
    int xq = quad ^ ((mr >> 2) & 3);
    f32x4 acc[4][4];
#pragma unroll
    for (int i = 0; i < 4; i++)
#pragma unroll
        for (int j = 0; j < 4; j++) acc[i][j] = (f32x4)0.f;

#define STAGE_D(b)                                                                        \
    do {                                                                                  \
        __builtin_amdgcn_global_load_lds(AS1(ap0), AS3(&As[b][0 + wv * 512]), 16, 0, 0);  \
        __builtin_amdgcn_global_load_lds(AS1(ap1), AS3(&As[b][2048 + wv * 512]), 16, 0,   \
                                         0);                                              \
        __builtin_amdgcn_global_load_lds(AS1(ap2), AS3(&As[b][4096 + wv * 512]), 16, 0,   \
                                         0);                                              \
        __builtin_amdgcn_global_load_lds(AS1(ap3), AS3(&As[b][6144 + wv * 512]), 16, 0,   \
                                         0);                                              \
        __builtin_amdgcn_global_load_lds(AS1(bp), AS3(&Bs[b][wv * 512]), 16, 0, 0);       \
        ap0 += 32; ap1 += 32; ap2 += 32; ap3 += 32; bp += 2048;                           \
    } while (0)

    STAGE_D(0);
    __syncthreads();
    int cur = 0;
    for (int ks = 0; ks < nk; ks++) {
        if (ks + 1 < nk) STAGE_D(cur ^ 1);
        const u16* Asc = As[cur];
        const u16* Bc = Bs[cur];
        short8 a0 = *(const short8*)(Asc + ((64 * wv + 0 + mr) * 4 + xq) * 8);
        short8 a1 = *(const short8*)(Asc + ((64 * wv + 16 + mr) * 4 + xq) * 8);
        short8 a2 = *(const short8*)(Asc + ((64 * wv + 32 + mr) * 4 + xq) * 8);
        short8 a3 = *(const short8*)(Asc + ((64 * wv + 48 + mr) * 4 + xq) * 8);
#pragma unroll
        for (int j = 0; j < 4; j++) {
            short8 b = *(const short8*)(Bc + ((16 * j + mr) * 4 + xq) * 8);
            acc[0][j] = __builtin_amdgcn_mfma_f32_16x16x32_bf16(a0, b, acc[0][j], 0, 0, 0);
            acc[1][j] = __builtin_amdgcn_mfma_f32_16x16x32_bf16(a1, b, acc[1][j], 0, 0, 0);
            acc[2][j] = __builtin_amdgcn_mfma_f32_16x16x32_bf16(a2, b, acc[2][j], 0, 0, 0);
            acc[3][j] = __builtin_amdgcn_mfma_f32_16x16x32_bf16(a3, b, acc[3][j], 0, 0, 0);
        }
        __syncthreads();
        cur ^= 1;
    }
#undef STAGE_D

#pragma unroll
    for (int i = 0; i < 4; i++)
#pragma unroll
        for (int j = 0; j < 4; j++)
#pragma unroll
            for (int r = 0; r < 4; r++) {
                int m = m0 + 64 * wv + 16 * i + quad * 4 + r;
                if (m >= cnt) continue;
                int n = n0 + 16 * j + mr;
                float v = acc[i][j][r];
                if (routed) {
                    outp[(size_t)(base + m) * HDIM + n] = v;  // per-slot, no atomics
                } else {
                    outp[(size_t)m * HDIM + n] = 0.1f * v;
                }
            }
}

// ---------------- combine: out[t] += w0*rd[slot0] + w1*rd[slot1] ----------------
__global__ __launch_bounds__(256) void combine_kernel(float* __restrict__ out,
                                                      const float* __restrict__ rd,
                                                      const int* __restrict__ tok2slot,
                                                      const float* __restrict__ top_w) {
    int t = blockIdx.x;
    int s0 = tok2slot[2 * t], s1 = tok2slot[2 * t + 1];
    float w0 = top_w[2 * t], w1 = top_w[2 * t + 1];
    const float4* r0 = (const float4*)(rd + (size_t)s0 * HDIM);
    const float4* r1 = (const float4*)(rd + (size_t)s1 * HDIM);
    float4* op = (float4*)(out + (size_t)t * HDIM);
#pragma unroll
    for (int k = 0; k < 2; k++) {
        int c = threadIdx.x + k * 256;
        float4 o = op[c];
        float4 a = r0[c];
        float4 b = r1[c];
        o.x += w0 * a.x + w1 * b.x;
        o.y += w0 * a.y + w1 * b.y;
        o.z += w0 * a.z + w1 * b.z;
        o.w += w0 * a.w + w1 * b.w;
        op[c] = o;
    }
}

extern "C" void kernel_launch(void* const* d_in, const int* in_sizes, int n_in,
                              void* d_out, int out_size, void* d_ws, size_t ws_size,
                              hipStream_t stream) {
    const float* x = (const float*)d_in[0];
    const float* cent = (const float*)d_in[1];
    const float* bias = (const float*)d_in[2];
    const float* wgs = (const float*)d_in[3];
    const float* wus = (const float*)d_in[4];
    const float* wds = (const float*)d_in[5];
    const float* wg = (const float*)d_in[6];
    const float* wu = (const float*)d_in[7];
    const float* wd = (const float*)d_in[8];
    float* out = (float*)d_out;
    char* ws = (char*)d_ws;

    size_t off_wtgs = 0;
    size_t off_wtus = off_wtgs + (size_t)HDIM * ISH * 2;
    size_t off_wtds = off_wtus + (size_t)HDIM * ISH * 2;
    size_t off_wtg = off_wtds + (size_t)ISH * HDIM * 2;
    size_t off_wtu = off_wtg + (size_t)NEXP * HDIM * IDIM * 2;
    size_t off_wtd = off_wtu + (size_t)NEXP * HDIM * IDIM * 2;
    size_t off_xbf = off_wtd + (size_t)NEXP * IDIM * HDIM * 2;
    size_t off_hsh = off_xbf + (size_t)TOKENS * HDIM * 2;
    size_t off_hrt = off_hsh + (size_t)TOKENS * ISH * 2;
    size_t off_meta = off_hrt + (size_t)2 * TOKENS * IDIM * 2;
    size_t need = off_meta + (1 << 20);
    if (ws_size < need) return;  // main path verified present in round 2

    u16* Wt_gs = (u16*)(ws + off_wtgs);
    u16* Wt_us = (u16*)(ws + off_wtus);
    u16* Wt_ds = (u16*)(ws + off_wtds);
    u16* Wt_g = (u16*)(ws + off_wtg);
    u16* Wt_u = (u16*)(ws + off_wtu);
    u16* Wt_d = (u16*)(ws + off_wtd);
    u16* x_bf = (u16*)(ws + off_xbf);
    u16* h_sh = (u16*)(ws + off_hsh);
    u16* h_rt = (u16*)(ws + off_hrt);
    // rd (67 MB, f32 [8192][2048]) OVERLAPS Wt_gs/Wt_us/Wt_ds + head of Wt_g:
    // every reader of those (shared gemms, routed gateup) completes before
    // routed gemm_down writes rd; conv_w rewrites the weights next iteration.
    float* rd = (float*)ws;
    int* counts = (int*)(ws + off_meta);
    int* offsets = counts + 16;
    int* ntiles = offsets + 16;
    int* tile_e = ntiles + 16;  // padding for alignment
    int* tile_m = tile_e + MAXTILES;
    int* tok2slot = tile_m + MAXTILES;
    int* top_e = tok2slot + 2 * TOKENS;
    float* top_w = (float*)(top_e + 2 * TOKENS);
    int* list_tok = (int*)(top_w + 2 * TOKENS);
    float* list_w = (float*)(list_tok + 2 * TOKENS);

    convert_x_kernel<<<TOKENS * HDIM / (256 * 8), 256, 0, stream>>>(x, x_bf);
    route_kernel<<<TOKENS / 4, 256, 0, stream>>>(x, cent, bias, top_e, top_w);
    build_kernel<<<1, 1024, 0, stream>>>(top_e, top_w, counts, offsets, ntiles, tile_e,
                                         tile_m, list_tok, list_w, tok2slot);

    conv_w_kernel<<<dim3(ISH / 64, HDIM / 256, 1), 256, 0, stream>>>(wgs, Wt_gs, HDIM, ISH);
    conv_w_kernel<<<dim3(ISH / 64, HDIM / 256, 1), 256, 0, stream>>>(wus, Wt_us, HDIM, ISH);
    conv_w_kernel<<<dim3(HDIM / 64, ISH / 256, 1), 256, 0, stream>>>(wds, Wt_ds, ISH, HDIM);
    conv_w_kernel<<<dim3(IDIM / 64, HDIM / 256, NEXP), 256, 0, stream>>>(wg, Wt_g, HDIM, IDIM);
    conv_w_kernel<<<dim3(IDIM / 64, HDIM / 256, NEXP), 256, 0, stream>>>(wu, Wt_u, HDIM, IDIM);
    conv_w_kernel<<<dim3(HDIM / 64, IDIM / 256, NEXP), 256, 0, stream>>>(wd, Wt_d, IDIM, HDIM);

    // shared expert (dense grids, M-tile 256)
    gemm_gateup<<<dim3(TOKENS / 256, ISH / 64, 1), 256, 0, stream>>>(
        x_bf, Wt_gs, Wt_us, h_sh, HDIM, ISH, nullptr, nullptr, nullptr, nullptr, nullptr,
        nullptr, 0);
    gemm_down<<<dim3(TOKENS / 256, HDIM / 64, 1), 256, 0, stream>>>(
        h_sh, Wt_ds, out, ISH, nullptr, nullptr, nullptr, nullptr, nullptr, nullptr, 0);
    // routed experts: dense 256-row tile-list grids
    gemm_gateup<<<dim3(MAXTILES, IDIM / 64, 1), 256, 0, stream>>>(
        x_bf, Wt_g, Wt_u, h_rt, HDIM, IDIM, counts, offsets, ntiles, tile_e, tile_m,
        list_tok, 1);
    gemm_down<<<dim3(MAXTILES, HDIM / 64, 1), 256, 0, stream>>>(
        h_rt, Wt_d, rd, IDIM, counts, offsets, ntiles, tile_e, tile_m, list_tok, 1);
    combine_kernel<<<TOKENS, 256, 0, stream>>>(out, rd, tok2slot, top_w);
}

// Round 6
// 980.684 us; speedup vs baseline: 1.1051x; 1.1051x over previous
//
#include <hip/hip_runtime.h>
#include <hip/hip_bf16.h>

typedef unsigned short u16;
typedef unsigned int u32;
typedef unsigned long long u64;
typedef __attribute__((ext_vector_type(8))) short short8;
typedef __attribute__((ext_vector_type(4))) float f32x4;

#define TOKENS 4096
#define HDIM 2048
#define NEXP 16
#define IDIM 1024
#define ISH 2048
#define MAXT128 80  // 128-row tiles: sum ceil(cnt_e/128) <= 64+16
#define MAXT256 48  // 256-row tiles: sum ceil(cnt_e/256) <= 32+16
#define NCHUNK 128  // 8192 route entries / 64 lanes

#define AS1(p) ((const __attribute__((address_space(1))) u32*)(p))
#define AS3(p) ((__attribute__((address_space(3))) u32*)(p))

__device__ __forceinline__ u16 f2b(float f) {
    u32 u = __float_as_uint(f);
    u32 r = u + 0x7fffu + ((u >> 16) & 1u);
    return (u16)(r >> 16);
}

// ---------------- convert x to bf16 ----------------
__global__ __launch_bounds__(256) void convert_x_kernel(const float* __restrict__ x,
                                                        u16* __restrict__ xb) {
    size_t i = ((size_t)blockIdx.x * 256 + threadIdx.x) * 8;
    float4 a = *(const float4*)(x + i);
    float4 b = *(const float4*)(x + i + 4);
    u32 p0 = (u32)f2b(a.x) | ((u32)f2b(a.y) << 16);
    u32 p1 = (u32)f2b(a.z) | ((u32)f2b(a.w) << 16);
    u32 p2 = (u32)f2b(b.x) | ((u32)f2b(b.y) << 16);
    u32 p3 = (u32)f2b(b.z) | ((u32)f2b(b.w) << 16);
    uint4 o = make_uint4(p0, p1, p2, p3);
    *(uint4*)(xb + i) = o;
}

// ---------------- routing: 1 wave per token, cent staged in LDS ----------------
__global__ __launch_bounds__(256) void route_kernel(const float* __restrict__ x,
                                                    const float* __restrict__ cent,
                                                    const float* __restrict__ bias,
                                                    int* __restrict__ top_e,
                                                    float* __restrict__ top_w) {
    __shared__ alignas(16) float cs[8 * 2048];  // 64KB: 8 experts per phase
    int lane = threadIdx.x & 63;
    int wv = threadIdx.x >> 6;
    int t = blockIdx.x * 4 + wv;
    const float4* xp4 = (const float4*)(x + (size_t)t * HDIM);
    float4 xr[8];
#pragma unroll
    for (int i = 0; i < 8; i++) xr[i] = xp4[lane + 64 * i];
    float aff[16];
#pragma unroll
    for (int ph = 0; ph < 2; ph++) {
        if (ph) __syncthreads();
        const float* sbase = cent + (size_t)(ph * 8 + wv * 2) * HDIM;
        float* dbase = cs + (size_t)wv * 2 * HDIM;
#pragma unroll
        for (int i = 0; i < 16; i++) {
            __builtin_amdgcn_global_load_lds(AS1(sbase + i * 256 + lane * 4),
                                             AS3(dbase + i * 256), 16, 0, 0);
        }
        __syncthreads();
#pragma unroll
        for (int e = 0; e < 8; e++) {
            const float4* cp = (const float4*)cs + (size_t)e * 512;
            float s = 0.f;
#pragma unroll
            for (int i = 0; i < 8; i++) {
                float4 cv = cp[lane + 64 * i];
                s += xr[i].x * cv.x;
                s += xr[i].y * cv.y;
                s += xr[i].z * cv.z;
                s += xr[i].w * cv.w;
            }
#pragma unroll
            for (int off = 32; off > 0; off >>= 1) s += __shfl_xor(s, off, 64);
            aff[ph * 8 + e] = 1.f / (1.f + expf(-s));
        }
    }
    float b0 = -1e30f, b1 = -1e30f, a0 = 0.f, a1 = 0.f;
    int e0 = -1, e1 = -1;
#pragma unroll
    for (int e = 0; e < 16; e++) {
        float v = aff[e] + bias[e];
        if (v > b0) {
            b1 = b0; e1 = e0; a1 = a0;
            b0 = v; e0 = e; a0 = aff[e];
        } else if (v > b1) {
            b1 = v; e1 = e; a1 = aff[e];
        }
    }
    float inv = 1.f / (a0 + a1 + 1e-9f);
    if (lane == 0) {
        top_e[2 * t] = e0; top_w[2 * t] = a0 * inv;
        top_e[2 * t + 1] = e1; top_w[2 * t + 1] = a1 * inv;
    }
}

// ---------------- build: histogram + scan + TWO tile lists + scatter ----------
__global__ __launch_bounds__(1024) void build_kernel(
    const int* __restrict__ top_e, const float* __restrict__ top_w,
    int* __restrict__ counts, int* __restrict__ offsets,
    int* __restrict__ ntilesA, int* __restrict__ tileA_e, int* __restrict__ tileA_m,
    int* __restrict__ ntilesB, int* __restrict__ tileB_e, int* __restrict__ tileB_m,
    int* __restrict__ list_tok, float* __restrict__ list_w,
    int* __restrict__ tok2slot) {
    __shared__ int cnt[NCHUNK][16];
    __shared__ int offs_s[16];
    __shared__ int totals[16];
    int tid = threadIdx.x;
    int lane = tid & 63, wv = tid >> 6;  // 16 waves
    for (int c = wv; c < NCHUNK; c += 16) {
        int v = top_e[c * 64 + lane];
#pragma unroll
        for (int e = 0; e < 16; e++) {
            u64 m = __ballot(v == e);
            if (lane == 0) cnt[c][e] = (int)__popcll(m);
        }
    }
    __syncthreads();
    if (tid < 16) {
        int s = 0;
        for (int c = 0; c < NCHUNK; c++) s += cnt[c][tid];
        totals[tid] = s;
        counts[tid] = s;
    }
    __syncthreads();
    if (tid == 0) {
        int r = 0, ntA = 0, ntB = 0;
        for (int e = 0; e < 16; e++) {
            offs_s[e] = r;
            offsets[e] = r;
            int ce = totals[e];
            int tA = (ce + 127) >> 7;
            for (int m = 0; m < tA; m++) { tileA_e[ntA] = e; tileA_m[ntA] = m; ntA++; }
            int tB = (ce + 255) >> 8;
            for (int m = 0; m < tB; m++) { tileB_e[ntB] = e; tileB_m[ntB] = m; ntB++; }
            r += ce;
        }
        *ntilesA = ntA;
        *ntilesB = ntB;
    }
    __syncthreads();
    if (tid < 16) {
        int r = offs_s[tid];
        for (int c = 0; c < NCHUNK; c++) {
            int v = cnt[c][tid];
            cnt[c][tid] = r;
            r += v;
        }
    }
    __syncthreads();
    for (int c = wv; c < NCHUNK; c += 16) {
        int i = c * 64 + lane;
        int v = top_e[i];
        int rank = 0;
#pragma unroll
        for (int e = 0; e < 16; e++) {
            u64 m = __ballot(v == e);
            if (v == e) rank = (int)__popcll(m & ((1ull << lane) - 1ull));
        }
        int slot = cnt[c][v] + rank;
        list_tok[slot] = i >> 1;
        list_w[slot] = top_w[i];
        tok2slot[i] = slot;
    }
}

// ================= MAIN PATH =================
// Convert fp32 W[K][N] -> bf16 tiled [N/64][K/32][64][32] with XOR swizzle.
__global__ __launch_bounds__(256) void conv_w_kernel(const float* __restrict__ W,
                                                     u16* __restrict__ Wt, int K, int N) {
    int nt = blockIdx.x, kc = blockIdx.y;
    size_t mato = (size_t)blockIdx.z * K * N;
    const float* Wm = W + mato;
    u16* Wtm = Wt + mato;
    int ksB = K >> 5;
    __shared__ u16 Ls[64 * 40];
    int t = threadIdx.x;
    int kr = t >> 3, ng = t & 7;
    int nn = t >> 2, seg = t & 3;
    int g = seg ^ ((nn >> 2) & 3);
#pragma unroll
    for (int s = 0; s < 8; s++) {
        int kb = kc * 256 + s * 32;
        const float* src = Wm + (size_t)(kb + kr) * N + nt * 64 + ng * 8;
        float4 f0 = *(const float4*)src;
        float4 f1 = *(const float4*)(src + 4);
        __syncthreads();
        const float* p0 = (const float*)&f0;
        const float* p1 = (const float*)&f1;
#pragma unroll
        for (int l = 0; l < 4; l++) Ls[(8 * ng + l) * 40 + kr] = f2b(p0[l]);
#pragma unroll
        for (int l = 0; l < 4; l++) Ls[(8 * ng + 4 + l) * 40 + kr] = f2b(p1[l]);
        __syncthreads();
        const u16* lp = &Ls[nn * 40 + g * 8];
        u32 w0 = (u32)lp[0] | ((u32)lp[1] << 16);
        u32 w1 = (u32)lp[2] | ((u32)lp[3] << 16);
        u32 w2 = (u32)lp[4] | ((u32)lp[5] << 16);
        u32 w3 = (u32)lp[6] | ((u32)lp[7] << 16);
        uint4 o = make_uint4(w0, w1, w2, w3);
        *(uint4*)(Wtm + (size_t)(nt * ksB + (kb >> 5)) * 2048 + t * 8) = o;
    }
}

// fused gate+up: M-tile 128, N-tile 64 (per matrix), BK 32, single LDS buffer.
// 64 AGPR + ~72 VGPR -> 3 waves/SIMD (round-5 lesson: M=256 dual-acc = 1 wave).
__global__ __launch_bounds__(256) void gemm_gateup(
    const u16* __restrict__ A, const u16* __restrict__ BgAll, const u16* __restrict__ BuAll,
    u16* __restrict__ hout, int Kd, int Nout, const int* __restrict__ counts,
    const int* __restrict__ offsets, const int* __restrict__ ntiles,
    const int* __restrict__ tile_e, const int* __restrict__ tile_m,
    const int* __restrict__ list_tok, int routed) {
    int cnt = TOKENS, base = 0, m0;
    const u16* Bg = BgAll;
    const u16* Bu = BuAll;
    if (routed) {
        int ti = blockIdx.x;
        if (ti >= *ntiles) return;
        int e = tile_e[ti];
        m0 = tile_m[ti] * 128;
        cnt = counts[e];
        base = offsets[e];
        size_t off = (size_t)e * Kd * Nout;
        Bg += off; Bu += off;
    } else {
        m0 = blockIdx.x * 128;
    }
    int ksB = Kd >> 5;
    __shared__ alignas(16) u16 As[128 * 32];
    __shared__ alignas(16) u16 Bgs[64 * 32];
    __shared__ alignas(16) u16 Bus[64 * 32];
    int tid = threadIdx.x;
    int lane = tid & 63, wv = tid >> 6;
    int quad = lane >> 4, mr = lane & 15;
    int n0 = blockIdx.y * 64;
    int gk = (tid & 3) ^ ((tid >> 4) & 3);
    int mg0 = min(m0 + (tid >> 2), cnt - 1);
    int mg1 = min(m0 + 64 + (tid >> 2), cnt - 1);
    size_t sr0 = routed ? (size_t)list_tok[base + mg0] : (size_t)mg0;
    size_t sr1 = routed ? (size_t)list_tok[base + mg1] : (size_t)mg1;
    const u16* ap0 = A + sr0 * Kd + gk * 8;
    const u16* ap1 = A + sr1 * Kd + gk * 8;
    const u16* bgp = Bg + (size_t)blockIdx.y * ksB * 2048 + tid * 8;
    const u16* bup = Bu + (size_t)blockIdx.y * ksB * 2048 + tid * 8;
    u16* AsW = As + wv * 512;
    u16* AsW2 = As + 2048 + wv * 512;
    u16* BgsW = Bgs + wv * 512;
    u16* BusW = Bus + wv * 512;
    int xq = quad ^ ((mr >> 2) & 3);
    const short8* a0p = (const short8*)(As + ((32 * wv + mr) * 4 + xq) * 8);
    const short8* a1p = (const short8*)(As + ((32 * wv + 16 + mr) * 4 + xq) * 8);
    f32x4 accg[2][4], accu[2][4];
#pragma unroll
    for (int i = 0; i < 2; i++)
#pragma unroll
        for (int j = 0; j < 4; j++) { accg[i][j] = (f32x4)0.f; accu[i][j] = (f32x4)0.f; }

    for (int ks = 0; ks < ksB; ks++) {
        __syncthreads();
        __builtin_amdgcn_global_load_lds(AS1(ap0), AS3(AsW), 16, 0, 0);
        __builtin_amdgcn_global_load_lds(AS1(ap1), AS3(AsW2), 16, 0, 0);
        __builtin_amdgcn_global_load_lds(AS1(bgp), AS3(BgsW), 16, 0, 0);
        __builtin_amdgcn_global_load_lds(AS1(bup), AS3(BusW), 16, 0, 0);
        ap0 += 32; ap1 += 32; bgp += 2048; bup += 2048;
        __syncthreads();
        short8 a0 = *a0p;
        short8 a1 = *a1p;
#pragma unroll
        for (int j = 0; j < 4; j++) {
            short8 bg = *(const short8*)(Bgs + (64 * j + mr * 4 + xq) * 8);
            short8 bu = *(const short8*)(Bus + (64 * j + mr * 4 + xq) * 8);
            accg[0][j] = __builtin_amdgcn_mfma_f32_16x16x32_bf16(a0, bg, accg[0][j], 0, 0, 0);
            accg[1][j] = __builtin_amdgcn_mfma_f32_16x16x32_bf16(a1, bg, accg[1][j], 0, 0, 0);
            accu[0][j] = __builtin_amdgcn_mfma_f32_16x16x32_bf16(a0, bu, accu[0][j], 0, 0, 0);
            accu[1][j] = __builtin_amdgcn_mfma_f32_16x16x32_bf16(a1, bu, accu[1][j], 0, 0, 0);
        }
    }
#pragma unroll
    for (int i = 0; i < 2; i++)
#pragma unroll
        for (int j = 0; j < 4; j++)
#pragma unroll
            for (int r = 0; r < 4; r++) {
                int m = m0 + 32 * wv + 16 * i + quad * 4 + r;
                if (m < cnt) {
                    float gv = accg[i][j][r], uv = accu[i][j][r];
                    float h = gv / (1.f + expf(-gv)) * uv;
                    int n = n0 + 16 * j + mr;
                    hout[(size_t)(base + m) * Nout + n] = f2b(h);
                }
            }
}

// down GEMM: M-tile 256, N-tile 64 (64 AGPR + ~60 VGPR -> 4 waves/SIMD).
// 2-buffer stage-early. routed: plain store into rd (combine gathers).
__global__ __launch_bounds__(256) void gemm_down(
    const u16* __restrict__ A, const u16* __restrict__ BAll, float* __restrict__ outp,
    int Kd, const int* __restrict__ counts, const int* __restrict__ offsets,
    const int* __restrict__ ntiles, const int* __restrict__ tile_e,
    const int* __restrict__ tile_m, const int* __restrict__ list_tok, int routed) {
    int cnt = TOKENS, base = 0, m0;
    const u16* B = BAll;
    if (routed) {
        int ti = blockIdx.x;
        if (ti >= *ntiles) return;
        int e = tile_e[ti];
        m0 = tile_m[ti] * 256;
        cnt = counts[e];
        base = offsets[e];
        B += (size_t)e * Kd * HDIM;
    } else {
        m0 = blockIdx.x * 256;
    }
    int nk = Kd >> 5;
    __shared__ alignas(16) u16 As[2][256 * 32];  // 16 KB each
    __shared__ alignas(16) u16 Bs[2][64 * 32];   // 4 KB each
    int tid = threadIdx.x;
    int lane = tid & 63, wv = tid >> 6;
    int quad = lane >> 4, mr = lane & 15;
    int n0 = blockIdx.y * 64;
    int gk = (tid & 3) ^ ((tid >> 4) & 3);
    const u16* ap0;
    const u16* ap1;
    const u16* ap2;
    const u16* ap3;
    {
        int mg0 = base + min(m0 + 0 * 64 + (tid >> 2), cnt - 1);
        int mg1 = base + min(m0 + 1 * 64 + (tid >> 2), cnt - 1);
        int mg2 = base + min(m0 + 2 * 64 + (tid >> 2), cnt - 1);
        int mg3 = base + min(m0 + 3 * 64 + (tid >> 2), cnt - 1);
        ap0 = A + (size_t)mg0 * Kd + gk * 8;
        ap1 = A + (size_t)mg1 * Kd + gk * 8;
        ap2 = A + (size_t)mg2 * Kd + gk * 8;
        ap3 = A + (size_t)mg3 * Kd + gk * 8;
    }
    const u16* bp = B + (size_t)blockIdx.y * nk * 2048 + tid * 8;
    int xq = quad ^ ((mr >> 2) & 3);
    f32x4 acc[4][4];
#pragma unroll
    for (int i = 0; i < 4; i++)
#pragma unroll
        for (int j = 0; j < 4; j++) acc[i][j] = (f32x4)0.f;

#define STAGE_D(b)                                                                        \
    do {                                                                                  \
        __builtin_amdgcn_global_load_lds(AS1(ap0), AS3(&As[b][0 + wv * 512]), 16, 0, 0);  \
        __builtin_amdgcn_global_load_lds(AS1(ap1), AS3(&As[b][2048 + wv * 512]), 16, 0,   \
                                         0);                                              \
        __builtin_amdgcn_global_load_lds(AS1(ap2), AS3(&As[b][4096 + wv * 512]), 16, 0,   \
                                         0);                                              \
        __builtin_amdgcn_global_load_lds(AS1(ap3), AS3(&As[b][6144 + wv * 512]), 16, 0,   \
                                         0);                                              \
        __builtin_amdgcn_global_load_lds(AS1(bp), AS3(&Bs[b][wv * 512]), 16, 0, 0);       \
        ap0 += 32; ap1 += 32; ap2 += 32; ap3 += 32; bp += 2048;                           \
    } while (0)

    STAGE_D(0);
    __syncthreads();
    int cur = 0;
    for (int ks = 0; ks < nk; ks++) {
        if (ks + 1 < nk) STAGE_D(cur ^ 1);
        const u16* Asc = As[cur];
        const u16* Bc = Bs[cur];
        short8 a0 = *(const short8*)(Asc + ((64 * wv + 0 + mr) * 4 + xq) * 8);
        short8 a1 = *(const short8*)(Asc + ((64 * wv + 16 + mr) * 4 + xq) * 8);
        short8 a2 = *(const short8*)(Asc + ((64 * wv + 32 + mr) * 4 + xq) * 8);
        short8 a3 = *(const short8*)(Asc + ((64 * wv + 48 + mr) * 4 + xq) * 8);
#pragma unroll
        for (int j = 0; j < 4; j++) {
            short8 b = *(const short8*)(Bc + ((16 * j + mr) * 4 + xq) * 8);
            acc[0][j] = __builtin_amdgcn_mfma_f32_16x16x32_bf16(a0, b, acc[0][j], 0, 0, 0);
            acc[1][j] = __builtin_amdgcn_mfma_f32_16x16x32_bf16(a1, b, acc[1][j], 0, 0, 0);
            acc[2][j] = __builtin_amdgcn_mfma_f32_16x16x32_bf16(a2, b, acc[2][j], 0, 0, 0);
            acc[3][j] = __builtin_amdgcn_mfma_f32_16x16x32_bf16(a3, b, acc[3][j], 0, 0, 0);
        }
        __syncthreads();
        cur ^= 1;
    }
#undef STAGE_D

#pragma unroll
    for (int i = 0; i < 4; i++)
#pragma unroll
        for (int j = 0; j < 4; j++)
#pragma unroll
            for (int r = 0; r < 4; r++) {
                int m = m0 + 64 * wv + 16 * i + quad * 4 + r;
                if (m >= cnt) continue;
                int n = n0 + 16 * j + mr;
                float v = acc[i][j][r];
                if (routed) {
                    outp[(size_t)(base + m) * HDIM + n] = v;  // per-slot, no atomics
                } else {
                    outp[(size_t)m * HDIM + n] = 0.1f * v;
                }
            }
}

// ---------------- combine: out[t] += w0*rd[slot0] + w1*rd[slot1] ----------------
__global__ __launch_bounds__(256) void combine_kernel(float* __restrict__ out,
                                                      const float* __restrict__ rd,
                                                      const int* __restrict__ tok2slot,
                                                      const float* __restrict__ top_w) {
    int t = blockIdx.x;
    int s0 = tok2slot[2 * t], s1 = tok2slot[2 * t + 1];
    float w0 = top_w[2 * t], w1 = top_w[2 * t + 1];
    const float4* r0 = (const float4*)(rd + (size_t)s0 * HDIM);
    const float4* r1 = (const float4*)(rd + (size_t)s1 * HDIM);
    float4* op = (float4*)(out + (size_t)t * HDIM);
#pragma unroll
    for (int k = 0; k < 2; k++) {
        int c = threadIdx.x + k * 256;
        float4 o = op[c];
        float4 a = r0[c];
        float4 b = r1[c];
        o.x += w0 * a.x + w1 * b.x;
        o.y += w0 * a.y + w1 * b.y;
        o.z += w0 * a.z + w1 * b.z;
        o.w += w0 * a.w + w1 * b.w;
        op[c] = o;
    }
}

extern "C" void kernel_launch(void* const* d_in, const int* in_sizes, int n_in,
                              void* d_out, int out_size, void* d_ws, size_t ws_size,
                              hipStream_t stream) {
    const float* x = (const float*)d_in[0];
    const float* cent = (const float*)d_in[1];
    const float* bias = (const float*)d_in[2];
    const float* wgs = (const float*)d_in[3];
    const float* wus = (const float*)d_in[4];
    const float* wds = (const float*)d_in[5];
    const float* wg = (const float*)d_in[6];
    const float* wu = (const float*)d_in[7];
    const float* wd = (const float*)d_in[8];
    float* out = (float*)d_out;
    char* ws = (char*)d_ws;

    size_t off_wtgs = 0;
    size_t off_wtus = off_wtgs + (size_t)HDIM * ISH * 2;
    size_t off_wtds = off_wtus + (size_t)HDIM * ISH * 2;
    size_t off_wtg = off_wtds + (size_t)ISH * HDIM * 2;
    size_t off_wtu = off_wtg + (size_t)NEXP * HDIM * IDIM * 2;
    size_t off_wtd = off_wtu + (size_t)NEXP * HDIM * IDIM * 2;
    size_t off_xbf = off_wtd + (size_t)NEXP * IDIM * HDIM * 2;
    size_t off_hsh = off_xbf + (size_t)TOKENS * HDIM * 2;
    size_t off_hrt = off_hsh + (size_t)TOKENS * ISH * 2;
    size_t off_meta = off_hrt + (size_t)2 * TOKENS * IDIM * 2;
    size_t need = off_meta + (1 << 20);
    if (ws_size < need) return;  // main path verified present in round 2

    u16* Wt_gs = (u16*)(ws + off_wtgs);
    u16* Wt_us = (u16*)(ws + off_wtus);
    u16* Wt_ds = (u16*)(ws + off_wtds);
    u16* Wt_g = (u16*)(ws + off_wtg);
    u16* Wt_u = (u16*)(ws + off_wtu);
    u16* Wt_d = (u16*)(ws + off_wtd);
    u16* x_bf = (u16*)(ws + off_xbf);
    u16* h_sh = (u16*)(ws + off_hsh);
    u16* h_rt = (u16*)(ws + off_hrt);
    // rd (67 MB, f32 [8192][2048]) OVERLAPS Wt_gs/Wt_us/Wt_ds + head of Wt_g:
    // every reader of those (shared gemms, routed gateup) completes (stream
    // order) before routed gemm_down writes rd; conv_w rewrites the weights
    // at the start of the next captured iteration.
    float* rd = (float*)ws;
    int* counts = (int*)(ws + off_meta);
    int* offsets = counts + 16;
    int* ntilesA = offsets + 16;
    int* ntilesB = ntilesA + 8;
    int* tileA_e = ntilesB + 8;
    int* tileA_m = tileA_e + MAXT128;
    int* tileB_e = tileA_m + MAXT128;
    int* tileB_m = tileB_e + MAXT256;
    int* tok2slot = tileB_m + MAXT256;
    int* top_e = tok2slot + 2 * TOKENS;
    float* top_w = (float*)(top_e + 2 * TOKENS);
    int* list_tok = (int*)(top_w + 2 * TOKENS);
    float* list_w = (float*)(list_tok + 2 * TOKENS);

    convert_x_kernel<<<TOKENS * HDIM / (256 * 8), 256, 0, stream>>>(x, x_bf);
    route_kernel<<<TOKENS / 4, 256, 0, stream>>>(x, cent, bias, top_e, top_w);
    build_kernel<<<1, 1024, 0, stream>>>(top_e, top_w, counts, offsets, ntilesA, tileA_e,
                                         tileA_m, ntilesB, tileB_e, tileB_m, list_tok,
                                         list_w, tok2slot);

    conv_w_kernel<<<dim3(ISH / 64, HDIM / 256, 1), 256, 0, stream>>>(wgs, Wt_gs, HDIM, ISH);
    conv_w_kernel<<<dim3(ISH / 64, HDIM / 256, 1), 256, 0, stream>>>(wus, Wt_us, HDIM, ISH);
    conv_w_kernel<<<dim3(HDIM / 64, ISH / 256, 1), 256, 0, stream>>>(wds, Wt_ds, ISH, HDIM);
    conv_w_kernel<<<dim3(IDIM / 64, HDIM / 256, NEXP), 256, 0, stream>>>(wg, Wt_g, HDIM, IDIM);
    conv_w_kernel<<<dim3(IDIM / 64, HDIM / 256, NEXP), 256, 0, stream>>>(wu, Wt_u, HDIM, IDIM);
    conv_w_kernel<<<dim3(HDIM / 64, IDIM / 256, NEXP), 256, 0, stream>>>(wd, Wt_d, IDIM, HDIM);

    // shared expert: gateup M=128 grid, down M=256 grid
    gemm_gateup<<<dim3(TOKENS / 128, ISH / 64, 1), 256, 0, stream>>>(
        x_bf, Wt_gs, Wt_us, h_sh, HDIM, ISH, nullptr, nullptr, nullptr, nullptr, nullptr,
        nullptr, 0);
    gemm_down<<<dim3(TOKENS / 256, HDIM / 64, 1), 256, 0, stream>>>(
        h_sh, Wt_ds, out, ISH, nullptr, nullptr, nullptr, nullptr, nullptr, nullptr, 0);
    // routed experts: gateup on 128-tiles, down on 256-tiles
    gemm_gateup<<<dim3(MAXT128, IDIM / 64, 1), 256, 0, stream>>>(
        x_bf, Wt_g, Wt_u, h_rt, HDIM, IDIM, counts, offsets, ntilesA, tileA_e, tileA_m,
        list_tok, 1);
    gemm_down<<<dim3(MAXT256, HDIM / 64, 1), 256, 0, stream>>>(
        h_rt, Wt_d, rd, IDIM, counts, offsets, ntilesB, tileB_e, tileB_m, list_tok, 1);
    combine_kernel<<<TOKENS, 256, 0, stream>>>(out, rd, tok2slot, top_w);
}

// Round 7
// 884.020 us; speedup vs baseline: 1.2259x; 1.1093x over previous
//
#include <hip/hip_runtime.h>
#include <hip/hip_bf16.h>

typedef unsigned short u16;
typedef unsigned int u32;
typedef unsigned long long u64;
typedef __attribute__((ext_vector_type(8))) short short8;
typedef __attribute__((ext_vector_type(4))) float f32x4;

#define TOKENS 4096
#define HDIM 2048
#define NEXP 16
#define IDIM 1024
#define ISH 2048
#define MAXT128 80  // 128-row tiles: sum ceil(cnt_e/128) <= 64+16
#define MAXT256 48  // 256-row tiles: sum ceil(cnt_e/256) <= 32+16
#define NCHUNK 128  // 8192 route entries / 64 lanes

#define AS1(p) ((const __attribute__((address_space(1))) u32*)(p))
#define AS3(p) ((__attribute__((address_space(3))) u32*)(p))

__device__ __forceinline__ u16 f2b(float f) {
    u32 u = __float_as_uint(f);
    u32 r = u + 0x7fffu + ((u >> 16) & 1u);
    return (u16)(r >> 16);
}

// ---------------- convert x to bf16 ----------------
__global__ __launch_bounds__(256) void convert_x_kernel(const float* __restrict__ x,
                                                        u16* __restrict__ xb) {
    size_t i = ((size_t)blockIdx.x * 256 + threadIdx.x) * 8;
    float4 a = *(const float4*)(x + i);
    float4 b = *(const float4*)(x + i + 4);
    u32 p0 = (u32)f2b(a.x) | ((u32)f2b(a.y) << 16);
    u32 p1 = (u32)f2b(a.z) | ((u32)f2b(a.w) << 16);
    u32 p2 = (u32)f2b(b.x) | ((u32)f2b(b.y) << 16);
    u32 p3 = (u32)f2b(b.z) | ((u32)f2b(b.w) << 16);
    uint4 o = make_uint4(p0, p1, p2, p3);
    *(uint4*)(xb + i) = o;
}

// ---------------- routing: 1 wave per token, cent staged in LDS ----------------
__global__ __launch_bounds__(256) void route_kernel(const float* __restrict__ x,
                                                    const float* __restrict__ cent,
                                                    const float* __restrict__ bias,
                                                    int* __restrict__ top_e,
                                                    float* __restrict__ top_w) {
    __shared__ alignas(16) float cs[8 * 2048];  // 64KB: 8 experts per phase
    int lane = threadIdx.x & 63;
    int wv = threadIdx.x >> 6;
    int t = blockIdx.x * 4 + wv;
    const float4* xp4 = (const float4*)(x + (size_t)t * HDIM);
    float4 xr[8];
#pragma unroll
    for (int i = 0; i < 8; i++) xr[i] = xp4[lane + 64 * i];
    float aff[16];
#pragma unroll
    for (int ph = 0; ph < 2; ph++) {
        if (ph) __syncthreads();
        const float* sbase = cent + (size_t)(ph * 8 + wv * 2) * HDIM;
        float* dbase = cs + (size_t)wv * 2 * HDIM;
#pragma unroll
        for (int i = 0; i < 16; i++) {
            __builtin_amdgcn_global_load_lds(AS1(sbase + i * 256 + lane * 4),
                                             AS3(dbase + i * 256), 16, 0, 0);
        }
        __syncthreads();
#pragma unroll
        for (int e = 0; e < 8; e++) {
            const float4* cp = (const float4*)cs + (size_t)e * 512;
            float s = 0.f;
#pragma unroll
            for (int i = 0; i < 8; i++) {
                float4 cv = cp[lane + 64 * i];
                s += xr[i].x * cv.x;
                s += xr[i].y * cv.y;
                s += xr[i].z * cv.z;
                s += xr[i].w * cv.w;
            }
#pragma unroll
            for (int off = 32; off > 0; off >>= 1) s += __shfl_xor(s, off, 64);
            aff[ph * 8 + e] = 1.f / (1.f + expf(-s));
        }
    }
    float b0 = -1e30f, b1 = -1e30f, a0 = 0.f, a1 = 0.f;
    int e0 = -1, e1 = -1;
#pragma unroll
    for (int e = 0; e < 16; e++) {
        float v = aff[e] + bias[e];
        if (v > b0) {
            b1 = b0; e1 = e0; a1 = a0;
            b0 = v; e0 = e; a0 = aff[e];
        } else if (v > b1) {
            b1 = v; e1 = e; a1 = aff[e];
        }
    }
    float inv = 1.f / (a0 + a1 + 1e-9f);
    if (lane == 0) {
        top_e[2 * t] = e0; top_w[2 * t] = a0 * inv;
        top_e[2 * t + 1] = e1; top_w[2 * t + 1] = a1 * inv;
    }
}

// ---------------- build: histogram + scan + TWO tile lists + scatter ----------
__global__ __launch_bounds__(1024) void build_kernel(
    const int* __restrict__ top_e, const float* __restrict__ top_w,
    int* __restrict__ counts, int* __restrict__ offsets,
    int* __restrict__ ntilesA, int* __restrict__ tileA_e, int* __restrict__ tileA_m,
    int* __restrict__ ntilesB, int* __restrict__ tileB_e, int* __restrict__ tileB_m,
    int* __restrict__ list_tok, float* __restrict__ list_w,
    int* __restrict__ tok2slot) {
    __shared__ int cnt[NCHUNK][16];
    __shared__ int offs_s[16];
    __shared__ int totals[16];
    int tid = threadIdx.x;
    int lane = tid & 63, wv = tid >> 6;  // 16 waves
    for (int c = wv; c < NCHUNK; c += 16) {
        int v = top_e[c * 64 + lane];
#pragma unroll
        for (int e = 0; e < 16; e++) {
            u64 m = __ballot(v == e);
            if (lane == 0) cnt[c][e] = (int)__popcll(m);
        }
    }
    __syncthreads();
    if (tid < 16) {
        int s = 0;
        for (int c = 0; c < NCHUNK; c++) s += cnt[c][tid];
        totals[tid] = s;
        counts[tid] = s;
    }
    __syncthreads();
    if (tid == 0) {
        int r = 0, ntA = 0, ntB = 0;
        for (int e = 0; e < 16; e++) {
            offs_s[e] = r;
            offsets[e] = r;
            int ce = totals[e];
            int tA = (ce + 127) >> 7;
            for (int m = 0; m < tA; m++) { tileA_e[ntA] = e; tileA_m[ntA] = m; ntA++; }
            int tB = (ce + 255) >> 8;
            for (int m = 0; m < tB; m++) { tileB_e[ntB] = e; tileB_m[ntB] = m; ntB++; }
            r += ce;
        }
        *ntilesA = ntA;
        *ntilesB = ntB;
    }
    __syncthreads();
    if (tid < 16) {
        int r = offs_s[tid];
        for (int c = 0; c < NCHUNK; c++) {
            int v = cnt[c][tid];
            cnt[c][tid] = r;
            r += v;
        }
    }
    __syncthreads();
    for (int c = wv; c < NCHUNK; c += 16) {
        int i = c * 64 + lane;
        int v = top_e[i];
        int rank = 0;
#pragma unroll
        for (int e = 0; e < 16; e++) {
            u64 m = __ballot(v == e);
            if (v == e) rank = (int)__popcll(m & ((1ull << lane) - 1ull));
        }
        int slot = cnt[c][v] + rank;
        list_tok[slot] = i >> 1;
        list_w[slot] = top_w[i];
        tok2slot[i] = slot;
    }
}

// ================= MAIN PATH =================
// Convert fp32 W[K][N] -> bf16 tiled [N/64][K/32][64][32] with XOR swizzle.
__global__ __launch_bounds__(256) void conv_w_kernel(const float* __restrict__ W,
                                                     u16* __restrict__ Wt, int K, int N) {
    int nt = blockIdx.x, kc = blockIdx.y;
    size_t mato = (size_t)blockIdx.z * K * N;
    const float* Wm = W + mato;
    u16* Wtm = Wt + mato;
    int ksB = K >> 5;
    __shared__ u16 Ls[64 * 40];
    int t = threadIdx.x;
    int kr = t >> 3, ng = t & 7;
    int nn = t >> 2, seg = t & 3;
    int g = seg ^ ((nn >> 2) & 3);
#pragma unroll
    for (int s = 0; s < 8; s++) {
        int kb = kc * 256 + s * 32;
        const float* src = Wm + (size_t)(kb + kr) * N + nt * 64 + ng * 8;
        float4 f0 = *(const float4*)src;
        float4 f1 = *(const float4*)(src + 4);
        __syncthreads();
        const float* p0 = (const float*)&f0;
        const float* p1 = (const float*)&f1;
#pragma unroll
        for (int l = 0; l < 4; l++) Ls[(8 * ng + l) * 40 + kr] = f2b(p0[l]);
#pragma unroll
        for (int l = 0; l < 4; l++) Ls[(8 * ng + 4 + l) * 40 + kr] = f2b(p1[l]);
        __syncthreads();
        const u16* lp = &Ls[nn * 40 + g * 8];
        u32 w0 = (u32)lp[0] | ((u32)lp[1] << 16);
        u32 w1 = (u32)lp[2] | ((u32)lp[3] << 16);
        u32 w2 = (u32)lp[4] | ((u32)lp[5] << 16);
        u32 w3 = (u32)lp[6] | ((u32)lp[7] << 16);
        uint4 o = make_uint4(w0, w1, w2, w3);
        *(uint4*)(Wtm + (size_t)(nt * ksB + (kb >> 5)) * 2048 + t * 8) = o;
    }
}

// fused gate+up: M-tile 128, N-tile 64 (per matrix), BK 64 (fatter K-steps:
// round-3/6 evidence shows time ~ step count, not step content).
// LDS 32 KB; 64 AGPR + ~76 VGPR -> 3 waves/SIMD unchanged.
__global__ __launch_bounds__(256) void gemm_gateup(
    const u16* __restrict__ A, const u16* __restrict__ BgAll, const u16* __restrict__ BuAll,
    u16* __restrict__ hout, int Kd, int Nout, const int* __restrict__ counts,
    const int* __restrict__ offsets, const int* __restrict__ ntiles,
    const int* __restrict__ tile_e, const int* __restrict__ tile_m,
    const int* __restrict__ list_tok, int routed) {
    int cnt = TOKENS, base = 0, m0;
    const u16* Bg = BgAll;
    const u16* Bu = BuAll;
    if (routed) {
        int ti = blockIdx.x;
        if (ti >= *ntiles) return;
        int e = tile_e[ti];
        m0 = tile_m[ti] * 128;
        cnt = counts[e];
        base = offsets[e];
        size_t off = (size_t)e * Kd * Nout;
        Bg += off; Bu += off;
    } else {
        m0 = blockIdx.x * 128;
    }
    int nk = Kd >> 6;  // BK=64 steps
    __shared__ alignas(16) u16 As[128 * 64];   // chunk c at c*4096 (128r x 32k)
    __shared__ alignas(16) u16 Bgs[64 * 64];   // chunk c at c*2048 (64n x 32k)
    __shared__ alignas(16) u16 Bus[64 * 64];
    int tid = threadIdx.x;
    int lane = tid & 63, wv = tid >> 6;
    int quad = lane >> 4, mr = lane & 15;
    int n0 = blockIdx.y * 64;
    int gk = (tid & 3) ^ ((tid >> 4) & 3);
    int mg0 = min(m0 + (tid >> 2), cnt - 1);
    int mg1 = min(m0 + 64 + (tid >> 2), cnt - 1);
    size_t sr0 = routed ? (size_t)list_tok[base + mg0] : (size_t)mg0;
    size_t sr1 = routed ? (size_t)list_tok[base + mg1] : (size_t)mg1;
    const u16* ap0 = A + sr0 * Kd + gk * 8;
    const u16* ap1 = A + sr1 * Kd + gk * 8;
    size_t bstr = (size_t)(Kd >> 5) * 2048;
    const u16* bgp = Bg + (size_t)blockIdx.y * bstr + tid * 8;
    const u16* bup = Bu + (size_t)blockIdx.y * bstr + tid * 8;
    int xq = quad ^ ((mr >> 2) & 3);
    f32x4 accg[2][4], accu[2][4];
#pragma unroll
    for (int i = 0; i < 2; i++)
#pragma unroll
        for (int j = 0; j < 4; j++) { accg[i][j] = (f32x4)0.f; accu[i][j] = (f32x4)0.f; }

    for (int ks = 0; ks < nk; ks++) {
        __syncthreads();
        // A: rows 0-63 (ap0) and 64-127 (ap1), k-chunks 0 and 1
        __builtin_amdgcn_global_load_lds(AS1(ap0), AS3(As + wv * 512), 16, 0, 0);
        __builtin_amdgcn_global_load_lds(AS1(ap0 + 32), AS3(As + 4096 + wv * 512), 16, 0, 0);
        __builtin_amdgcn_global_load_lds(AS1(ap1), AS3(As + 2048 + wv * 512), 16, 0, 0);
        __builtin_amdgcn_global_load_lds(AS1(ap1 + 32), AS3(As + 6144 + wv * 512), 16, 0, 0);
        __builtin_amdgcn_global_load_lds(AS1(bgp), AS3(Bgs + wv * 512), 16, 0, 0);
        __builtin_amdgcn_global_load_lds(AS1(bgp + 2048), AS3(Bgs + 2048 + wv * 512), 16, 0, 0);
        __builtin_amdgcn_global_load_lds(AS1(bup), AS3(Bus + wv * 512), 16, 0, 0);
        __builtin_amdgcn_global_load_lds(AS1(bup + 2048), AS3(Bus + 2048 + wv * 512), 16, 0, 0);
        ap0 += 64; ap1 += 64; bgp += 4096; bup += 4096;
        __syncthreads();
#pragma unroll
        for (int c = 0; c < 2; c++) {
            short8 a0 = *(const short8*)(As + c * 4096 + ((32 * wv + mr) * 4 + xq) * 8);
            short8 a1 = *(const short8*)(As + c * 4096 + ((32 * wv + 16 + mr) * 4 + xq) * 8);
#pragma unroll
            for (int j = 0; j < 4; j++) {
                short8 bg = *(const short8*)(Bgs + c * 2048 + (64 * j + mr * 4 + xq) * 8);
                short8 bu = *(const short8*)(Bus + c * 2048 + (64 * j + mr * 4 + xq) * 8);
                accg[0][j] = __builtin_amdgcn_mfma_f32_16x16x32_bf16(a0, bg, accg[0][j], 0, 0, 0);
                accg[1][j] = __builtin_amdgcn_mfma_f32_16x16x32_bf16(a1, bg, accg[1][j], 0, 0, 0);
                accu[0][j] = __builtin_amdgcn_mfma_f32_16x16x32_bf16(a0, bu, accu[0][j], 0, 0, 0);
                accu[1][j] = __builtin_amdgcn_mfma_f32_16x16x32_bf16(a1, bu, accu[1][j], 0, 0, 0);
            }
        }
    }
#pragma unroll
    for (int i = 0; i < 2; i++)
#pragma unroll
        for (int j = 0; j < 4; j++)
#pragma unroll
            for (int r = 0; r < 4; r++) {
                int m = m0 + 32 * wv + 16 * i + quad * 4 + r;
                if (m < cnt) {
                    float gv = accg[i][j][r], uv = accu[i][j][r];
                    float h = gv / (1.f + expf(-gv)) * uv;
                    int n = n0 + 16 * j + mr;
                    hout[(size_t)(base + m) * Nout + n] = f2b(h);
                }
            }
}

// down GEMM: M-tile 256, N-tile 64, BK 64, single 40 KB LDS buffer.
// 64 AGPR + ~70 VGPR -> 4 waves/SIMD; LDS-limit 4 blocks/CU.
__global__ __launch_bounds__(256) void gemm_down(
    const u16* __restrict__ A, const u16* __restrict__ BAll, float* __restrict__ outp,
    int Kd, const int* __restrict__ counts, const int* __restrict__ offsets,
    const int* __restrict__ ntiles, const int* __restrict__ tile_e,
    const int* __restrict__ tile_m, const int* __restrict__ list_tok, int routed) {
    int cnt = TOKENS, base = 0, m0;
    const u16* B = BAll;
    if (routed) {
        int ti = blockIdx.x;
        if (ti >= *ntiles) return;
        int e = tile_e[ti];
        m0 = tile_m[ti] * 256;
        cnt = counts[e];
        base = offsets[e];
        B += (size_t)e * Kd * HDIM;
    } else {
        m0 = blockIdx.x * 256;
    }
    int nk = Kd >> 6;  // BK=64
    __shared__ alignas(16) u16 As[256 * 64];  // 32 KB: chunk c at c*8192 (256r x 32k)
    __shared__ alignas(16) u16 Bs[64 * 64];   // 8 KB: chunk c at c*2048
    int tid = threadIdx.x;
    int lane = tid & 63, wv = tid >> 6;
    int quad = lane >> 4, mr = lane & 15;
    int n0 = blockIdx.y * 64;
    int gk = (tid & 3) ^ ((tid >> 4) & 3);
    const u16* ap0;
    const u16* ap1;
    const u16* ap2;
    const u16* ap3;
    {
        int mg0 = base + min(m0 + 0 * 64 + (tid >> 2), cnt - 1);
        int mg1 = base + min(m0 + 1 * 64 + (tid >> 2), cnt - 1);
        int mg2 = base + min(m0 + 2 * 64 + (tid >> 2), cnt - 1);
        int mg3 = base + min(m0 + 3 * 64 + (tid >> 2), cnt - 1);
        ap0 = A + (size_t)mg0 * Kd + gk * 8;
        ap1 = A + (size_t)mg1 * Kd + gk * 8;
        ap2 = A + (size_t)mg2 * Kd + gk * 8;
        ap3 = A + (size_t)mg3 * Kd + gk * 8;
    }
    size_t bstr = (size_t)(Kd >> 5) * 2048;
    const u16* bp = B + (size_t)blockIdx.y * bstr + tid * 8;
    int xq = quad ^ ((mr >> 2) & 3);
    f32x4 acc[4][4];
#pragma unroll
    for (int i = 0; i < 4; i++)
#pragma unroll
        for (int j = 0; j < 4; j++) acc[i][j] = (f32x4)0.f;

    for (int ks = 0; ks < nk; ks++) {
        __syncthreads();
        __builtin_amdgcn_global_load_lds(AS1(ap0), AS3(As + 0 + wv * 512), 16, 0, 0);
        __builtin_amdgcn_global_load_lds(AS1(ap0 + 32), AS3(As + 8192 + wv * 512), 16, 0, 0);
        __builtin_amdgcn_global_load_lds(AS1(ap1), AS3(As + 2048 + wv * 512), 16, 0, 0);
        __builtin_amdgcn_global_load_lds(AS1(ap1 + 32), AS3(As + 10240 + wv * 512), 16, 0, 0);
        __builtin_amdgcn_global_load_lds(AS1(ap2), AS3(As + 4096 + wv * 512), 16, 0, 0);
        __builtin_amdgcn_global_load_lds(AS1(ap2 + 32), AS3(As + 12288 + wv * 512), 16, 0, 0);
        __builtin_amdgcn_global_load_lds(AS1(ap3), AS3(As + 6144 + wv * 512), 16, 0, 0);
        __builtin_amdgcn_global_load_lds(AS1(ap3 + 32), AS3(As + 14336 + wv * 512), 16, 0, 0);
        __builtin_amdgcn_global_load_lds(AS1(bp), AS3(Bs + wv * 512), 16, 0, 0);
        __builtin_amdgcn_global_load_lds(AS1(bp + 2048), AS3(Bs + 2048 + wv * 512), 16, 0, 0);
        ap0 += 64; ap1 += 64; ap2 += 64; ap3 += 64; bp += 4096;
        __syncthreads();
#pragma unroll
        for (int c = 0; c < 2; c++) {
            short8 a0 = *(const short8*)(As + c * 8192 + ((64 * wv + 0 + mr) * 4 + xq) * 8);
            short8 a1 = *(const short8*)(As + c * 8192 + ((64 * wv + 16 + mr) * 4 + xq) * 8);
            short8 a2 = *(const short8*)(As + c * 8192 + ((64 * wv + 32 + mr) * 4 + xq) * 8);
            short8 a3 = *(const short8*)(As + c * 8192 + ((64 * wv + 48 + mr) * 4 + xq) * 8);
#pragma unroll
            for (int j = 0; j < 4; j++) {
                short8 b = *(const short8*)(Bs + c * 2048 + (64 * j + mr * 4 + xq) * 8);
                acc[0][j] = __builtin_amdgcn_mfma_f32_16x16x32_bf16(a0, b, acc[0][j], 0, 0, 0);
                acc[1][j] = __builtin_amdgcn_mfma_f32_16x16x32_bf16(a1, b, acc[1][j], 0, 0, 0);
                acc[2][j] = __builtin_amdgcn_mfma_f32_16x16x32_bf16(a2, b, acc[2][j], 0, 0, 0);
                acc[3][j] = __builtin_amdgcn_mfma_f32_16x16x32_bf16(a3, b, acc[3][j], 0, 0, 0);
            }
        }
    }

#pragma unroll
    for (int i = 0; i < 4; i++)
#pragma unroll
        for (int j = 0; j < 4; j++)
#pragma unroll
            for (int r = 0; r < 4; r++) {
                int m = m0 + 64 * wv + 16 * i + quad * 4 + r;
                if (m >= cnt) continue;
                int n = n0 + 16 * j + mr;
                float v = acc[i][j][r];
                if (routed) {
                    outp[(size_t)(base + m) * HDIM + n] = v;  // per-slot, no atomics
                } else {
                    outp[(size_t)m * HDIM + n] = 0.1f * v;
                }
            }
}

// ---------------- combine: out[t] += w0*rd[slot0] + w1*rd[slot1] ----------------
__global__ __launch_bounds__(256) void combine_kernel(float* __restrict__ out,
                                                      const float* __restrict__ rd,
                                                      const int* __restrict__ tok2slot,
                                                      const float* __restrict__ top_w) {
    int t = blockIdx.x;
    int s0 = tok2slot[2 * t], s1 = tok2slot[2 * t + 1];
    float w0 = top_w[2 * t], w1 = top_w[2 * t + 1];
    const float4* r0 = (const float4*)(rd + (size_t)s0 * HDIM);
    const float4* r1 = (const float4*)(rd + (size_t)s1 * HDIM);
    float4* op = (float4*)(out + (size_t)t * HDIM);
#pragma unroll
    for (int k = 0; k < 2; k++) {
        int c = threadIdx.x + k * 256;
        float4 o = op[c];
        float4 a = r0[c];
        float4 b = r1[c];
        o.x += w0 * a.x + w1 * b.x;
        o.y += w0 * a.y + w1 * b.y;
        o.z += w0 * a.z + w1 * b.z;
        o.w += w0 * a.w + w1 * b.w;
        op[c] = o;
    }
}

extern "C" void kernel_launch(void* const* d_in, const int* in_sizes, int n_in,
                              void* d_out, int out_size, void* d_ws, size_t ws_size,
                              hipStream_t stream) {
    const float* x = (const float*)d_in[0];
    const float* cent = (const float*)d_in[1];
    const float* bias = (const float*)d_in[2];
    const float* wgs = (const float*)d_in[3];
    const float* wus = (const float*)d_in[4];
    const float* wds = (const float*)d_in[5];
    const float* wg = (const float*)d_in[6];
    const float* wu = (const float*)d_in[7];
    const float* wd = (const float*)d_in[8];
    float* out = (float*)d_out;
    char* ws = (char*)d_ws;

    size_t off_wtgs = 0;
    size_t off_wtus = off_wtgs + (size_t)HDIM * ISH * 2;
    size_t off_wtds = off_wtus + (size_t)HDIM * ISH * 2;
    size_t off_wtg = off_wtds + (size_t)ISH * HDIM * 2;
    size_t off_wtu = off_wtg + (size_t)NEXP * HDIM * IDIM * 2;
    size_t off_wtd = off_wtu + (size_t)NEXP * HDIM * IDIM * 2;
    size_t off_xbf = off_wtd + (size_t)NEXP * IDIM * HDIM * 2;
    size_t off_hsh = off_xbf + (size_t)TOKENS * HDIM * 2;
    size_t off_hrt = off_hsh + (size_t)TOKENS * ISH * 2;
    size_t off_meta = off_hrt + (size_t)2 * TOKENS * IDIM * 2;
    size_t need = off_meta + (1 << 20);
    if (ws_size < need) return;  // main path verified present in round 2

    u16* Wt_gs = (u16*)(ws + off_wtgs);
    u16* Wt_us = (u16*)(ws + off_wtus);
    u16* Wt_ds = (u16*)(ws + off_wtds);
    u16* Wt_g = (u16*)(ws + off_wtg);
    u16* Wt_u = (u16*)(ws + off_wtu);
    u16* Wt_d = (u16*)(ws + off_wtd);
    u16* x_bf = (u16*)(ws + off_xbf);
    u16* h_sh = (u16*)(ws + off_hsh);
    u16* h_rt = (u16*)(ws + off_hrt);
    // rd (67 MB, f32 [8192][2048]) OVERLAPS Wt_gs/Wt_us/Wt_ds + head of Wt_g:
    // every reader of those (shared gemms, routed gateup) completes (stream
    // order) before routed gemm_down writes rd; conv_w rewrites the weights
    // at the start of the next captured iteration.
    float* rd = (float*)ws;
    int* counts = (int*)(ws + off_meta);
    int* offsets = counts + 16;
    int* ntilesA = offsets + 16;
    int* ntilesB = ntilesA + 8;
    int* tileA_e = ntilesB + 8;
    int* tileA_m = tileA_e + MAXT128;
    int* tileB_e = tileA_m + MAXT128;
    int* tileB_m = tileB_e + MAXT256;
    int* tok2slot = tileB_m + MAXT256;
    int* top_e = tok2slot + 2 * TOKENS;
    float* top_w = (float*)(top_e + 2 * TOKENS);
    int* list_tok = (int*)(top_w + 2 * TOKENS);
    float* list_w = (float*)(list_tok + 2 * TOKENS);

    convert_x_kernel<<<TOKENS * HDIM / (256 * 8), 256, 0, stream>>>(x, x_bf);
    route_kernel<<<TOKENS / 4, 256, 0, stream>>>(x, cent, bias, top_e, top_w);
    build_kernel<<<1, 1024, 0, stream>>>(top_e, top_w, counts, offsets, ntilesA, tileA_e,
                                         tileA_m, ntilesB, tileB_e, tileB_m, list_tok,
                                         list_w, tok2slot);

    conv_w_kernel<<<dim3(ISH / 64, HDIM / 256, 1), 256, 0, stream>>>(wgs, Wt_gs, HDIM, ISH);
    conv_w_kernel<<<dim3(ISH / 64, HDIM / 256, 1), 256, 0, stream>>>(wus, Wt_us, HDIM, ISH);
    conv_w_kernel<<<dim3(HDIM / 64, ISH / 256, 1), 256, 0, stream>>>(wds, Wt_ds, ISH, HDIM);
    conv_w_kernel<<<dim3(IDIM / 64, HDIM / 256, NEXP), 256, 0, stream>>>(wg, Wt_g, HDIM, IDIM);
    conv_w_kernel<<<dim3(IDIM / 64, HDIM / 256, NEXP), 256, 0, stream>>>(wu, Wt_u, HDIM, IDIM);
    conv_w_kernel<<<dim3(HDIM / 64, IDIM / 256, NEXP), 256, 0, stream>>>(wd, Wt_d, IDIM, HDIM);

    // shared expert: gateup M=128 grid, down M=256 grid
    gemm_gateup<<<dim3(TOKENS / 128, ISH / 64, 1), 256, 0, stream>>>(
        x_bf, Wt_gs, Wt_us, h_sh, HDIM, ISH, nullptr, nullptr, nullptr, nullptr, nullptr,
        nullptr, 0);
    gemm_down<<<dim3(TOKENS / 256, HDIM / 64, 1), 256, 0, stream>>>(
        h_sh, Wt_ds, out, ISH, nullptr, nullptr, nullptr, nullptr, nullptr, nullptr, 0);
    // routed experts: gateup on 128-tiles, down on 256-tiles
    gemm_gateup<<<dim3(MAXT128, IDIM / 64, 1), 256, 0, stream>>>(
        x_bf, Wt_g, Wt_u, h_rt, HDIM, IDIM, counts, offsets, ntilesA, tileA_e, tileA_m,
        list_tok, 1);
    gemm_down<<<dim3(MAXT256, HDIM / 64, 1), 256, 0, stream>>>(
        h_rt, Wt_d, rd, IDIM, counts, offsets, ntilesB, tileB_e, tileB_m, list_tok, 1);
    combine_kernel<<<TOKENS, 256, 0, stream>>>(out, rd, tok2slot, top_w);
}